// Round 8
// baseline (1019.294 us; speedup 1.0000x reference)
//
#include <hip/hip_runtime.h>
#include <math.h>

#define DIM 384
#define HEADS 12
#define MTOT 65536  // total tokens = 16*64*64

typedef _Float16 f16;
typedef f16 f16x8 __attribute__((ext_vector_type(8)));
typedef float f32x4 __attribute__((ext_vector_type(4)));

typedef const __attribute__((address_space(1))) unsigned int* gas1;
typedef __attribute__((address_space(3))) unsigned int* las3;

// ---------- LayerNorm (+ optional shifted-window gather), fp16 out ----------
template<bool GATHER>
__global__ __launch_bounds__(128)
void ln_kernel(const float* __restrict__ x, const float* __restrict__ g,
               const float* __restrict__ b, f16* __restrict__ y)
{
    int r = blockIdx.x;
    size_t src;
    if (GATHER) {
        int win = r >> 6, tok = r & 63;
        int wd = win >> 8, wh = (win >> 4) & 15, ww = win & 15;
        int zd = tok >> 4, zh = (tok >> 2) & 3, zw = tok & 3;
        int d = ((wd << 2) + zd + 2) & 15;
        int h = ((wh << 2) + zh + 2) & 63;
        int w = ((ww << 2) + zw + 2) & 63;
        src = (size_t)((((d << 6) + h) << 6) + w);
    } else {
        src = (size_t)r;
    }
    const float* xr = x + src * (size_t)DIM;
    int t = threadIdx.x;
    float v0 = xr[t], v1 = xr[t + 128], v2 = xr[t + 256];
    float s  = v0 + v1 + v2;
    float ss = v0 * v0 + v1 * v1 + v2 * v2;
    #pragma unroll
    for (int off = 32; off > 0; off >>= 1) {
        s  += __shfl_down(s, off);
        ss += __shfl_down(ss, off);
    }
    __shared__ float sm[4];
    if ((t & 63) == 0) { sm[t >> 6] = s; sm[2 + (t >> 6)] = ss; }
    __syncthreads();
    float S = sm[0] + sm[1], SS = sm[2] + sm[3];
    float mu  = S * (1.0f / DIM);
    float var = SS * (1.0f / DIM) - mu * mu;
    float rs  = rsqrtf(var + 1e-5f);
    f16* yr = y + (size_t)r * DIM;
    yr[t]       = (f16)((v0 - mu) * rs * g[t]       + b[t]);
    yr[t + 128] = (f16)((v1 - mu) * rs * g[t + 128] + b[t + 128]);
    yr[t + 256] = (f16)((v2 - mu) * rs * g[t + 256] + b[t + 256]);
}

// ---------- weight convert + transpose: W[K][N] fp32 -> Wt[N][K] fp16 ----------
__global__ __launch_bounds__(128)
void wcvt_kernel(const float* __restrict__ W, f16* __restrict__ Wt, int N, int K)
{
    int k = blockIdx.x * 128 + threadIdx.x;
    int n = blockIdx.y;
    Wt[(size_t)n * K + k] = (f16)W[(size_t)k * N + n];
}

// ---------- staging helper for proj GEMM (validated R5 structure) ----------
__device__ __forceinline__ void stage_pair(const f16* __restrict__ Ag, const f16* __restrict__ Bg,
                                           f16* Asb, f16* Bsb, int K, int kt, int wv, int lane)
{
    #pragma unroll
    for (int i = 0; i < 2; ++i) {
        int r  = wv * 32 + i * 16 + (lane >> 2);
        int c  = lane & 3;
        int gc = c ^ ((r >> 1) & 3);
        const f16* ga = Ag + (size_t)r * K + kt * 32 + gc * 8;
        const f16* gb = Bg + (size_t)r * K + kt * 32 + gc * 8;
        __builtin_amdgcn_global_load_lds((gas1)ga, (las3)(Asb + r * 32 + c * 8), 16, 0, 0);
        __builtin_amdgcn_global_load_lds((gas1)gb, (las3)(Bsb + r * 32 + c * 8), 16, 0, 0);
    }
}

// ---------- proj GEMM (EPI2 only): +bias, window-reverse+roll scatter, +=res ----
__global__ __launch_bounds__(256)
void gemm_kernel(const f16* __restrict__ A, const f16* __restrict__ Wt,
                 const float* __restrict__ bias, const float* __restrict__ res,
                 float* __restrict__ outv, int N, int K)
{
    __shared__ f16 As[3][128 * 32];
    __shared__ f16 Bs[3][128 * 32];
    int tid = threadIdx.x;
    int lane = tid & 63, wv = tid >> 6;
    int bm = blockIdx.y << 7, bn = blockIdx.x << 7;
    int fr = lane & 15, fq = lane >> 4;
    int wr = wv >> 1, wc = wv & 1;

    const f16* Ag = A  + (size_t)bm * K;
    const f16* Bg = Wt + (size_t)bn * K;

    f32x4 zero4 = {0.f, 0.f, 0.f, 0.f};
    f32x4 acc[4][4];
    #pragma unroll
    for (int i = 0; i < 4; ++i)
        #pragma unroll
        for (int j = 0; j < 4; ++j) acc[i][j] = zero4;

    int nk = K >> 5;
    stage_pair(Ag, Bg, As[0], Bs[0], K, 0, wv, lane);
    stage_pair(Ag, Bg, As[1], Bs[1], K, 1, wv, lane);
    int cur = 0;
    for (int t = 0; t < nk; ++t) {
        if (t + 1 < nk) asm volatile("s_waitcnt vmcnt(4)" ::: "memory");
        else            asm volatile("s_waitcnt vmcnt(0)" ::: "memory");
        __builtin_amdgcn_s_barrier();
        if (t + 2 < nk) {
            int nxt = cur + 2; if (nxt >= 3) nxt -= 3;
            stage_pair(Ag, Bg, As[nxt], Bs[nxt], K, t + 2, wv, lane);
        }
        f16x8 a[4], b[4];
        #pragma unroll
        for (int i = 0; i < 4; ++i) {
            int R  = wr * 64 + i * 16 + fr;
            int Nn = wc * 64 + i * 16 + fr;
            a[i] = *(const f16x8*)&As[cur][R  * 32 + (fq ^ ((R  >> 1) & 3)) * 8];
            b[i] = *(const f16x8*)&Bs[cur][Nn * 32 + (fq ^ ((Nn >> 1) & 3)) * 8];
        }
        __builtin_amdgcn_s_setprio(1);
        #pragma unroll
        for (int i = 0; i < 4; ++i)
            #pragma unroll
            for (int j = 0; j < 4; ++j)
                acc[i][j] = __builtin_amdgcn_mfma_f32_16x16x32_f16(a[i], b[j], acc[i][j], 0, 0, 0);
        __builtin_amdgcn_s_setprio(0);
        cur = (cur == 2) ? 0 : cur + 1;
    }

    #pragma unroll
    for (int i = 0; i < 4; ++i) {
        int mrow = bm + wr * 64 + i * 16 + fq * 4;
        #pragma unroll
        for (int j = 0; j < 4; ++j) {
            int n = bn + wc * 64 + j * 16 + fr;
            float bi = bias[n];
            #pragma unroll
            for (int r = 0; r < 4; ++r) {
                int m = mrow + r;
                int win = m >> 6, tok = m & 63;
                int wd = win >> 8, wh = (win >> 4) & 15, ww = win & 15;
                int zd = tok >> 4, zh = (tok >> 2) & 3, zw = tok & 3;
                int d = ((wd << 2) + zd + 2) & 15;
                int h = ((wh << 2) + zh + 2) & 63;
                int w = ((ww << 2) + zw + 2) & 63;
                size_t orow = (size_t)((((d << 6) + h) << 6) + w);
                outv[orow * DIM + n] = acc[i][j][r] + bi + res[orow * DIM + n];
            }
        }
    }
}

// ---------- fused QKV + windowed attention: one block per window ----------
// Reads Yh (y_win rows), writes O back into the same rows (block-exclusive).
__global__ __launch_bounds__(256)
void fqa_kernel(f16* __restrict__ Yh, const f16* __restrict__ wt,
                const float* __restrict__ qbias, const float* __restrict__ rpb)
{
    __shared__ f16 y_s[64][392];    // y window, padded
    __shared__ f16 q_s[2][64][40];  // per head-pair: Q (scaled), padded
    __shared__ f16 k_s[2][64][40];
    __shared__ f16 vt_s[2][32][72]; // V transposed [hd][token]
    __shared__ f16 P[64][72];       // softmax probs (per head, own-wave rows)
    int win = blockIdx.x;
    int tid = threadIdx.x, lane = tid & 63, wv = tid >> 6;
    int fr = lane & 15, fq = lane >> 4;
    const float scale = 0.17677669529663687f;  // 32^-0.5
    f16* yg = Yh + (size_t)win * 64 * DIM;

    // stage y window -> LDS (4 threads/row, 96 halves each)
    {
        int row = tid >> 2, c0 = (tid & 3) * 96;
        #pragma unroll
        for (int i = 0; i < 12; ++i)
            *(f16x8*)&y_s[row][c0 + i * 8] = *(const f16x8*)(yg + row * DIM + c0 + i * 8);
    }
    __syncthreads();

    f32x4 zero4 = {0.f, 0.f, 0.f, 0.f};
    for (int hp = 0; hp < 6; ++hp) {
        // ---- QKV GEMM for head pair: 12 n-frags, wave wv owns nf = wv*3..+2
        f32x4 acc[3][4];
        #pragma unroll
        for (int jn = 0; jn < 3; ++jn)
            #pragma unroll
            for (int i = 0; i < 4; ++i) acc[jn][i] = zero4;
        #pragma unroll
        for (int kk = 0; kk < 12; ++kk) {
            f16x8 a[4];
            #pragma unroll
            for (int i = 0; i < 4; ++i)
                a[i] = *(const f16x8*)&y_s[i * 16 + fr][kk * 32 + fq * 8];
            #pragma unroll
            for (int jn = 0; jn < 3; ++jn) {
                int nf = wv * 3 + jn;
                int which = nf >> 1, tp = which >> 1, hh = which & 1;
                int gcol = tp * 384 + (hp * 2 + hh) * 32 + (nf & 1) * 16 + fr;
                f16x8 b = *(const f16x8*)(wt + (size_t)gcol * 384 + kk * 32 + fq * 8);
                #pragma unroll
                for (int i = 0; i < 4; ++i)
                    acc[jn][i] = __builtin_amdgcn_mfma_f32_16x16x32_f16(a[i], b, acc[jn][i], 0, 0, 0);
            }
        }
        // ---- bias (+scale for Q) -> LDS tiles
        #pragma unroll
        for (int jn = 0; jn < 3; ++jn) {
            int nf = wv * 3 + jn;
            int which = nf >> 1, tp = which >> 1, hh = which & 1;
            int colhd = (nf & 1) * 16 + fr;
            float bi = qbias[tp * 384 + (hp * 2 + hh) * 32 + colhd];
            #pragma unroll
            for (int i = 0; i < 4; ++i)
                #pragma unroll
                for (int r = 0; r < 4; ++r) {
                    int row = i * 16 + fq * 4 + r;
                    float v = acc[jn][i][r] + bi;
                    if (tp == 0)      q_s[hh][row][colhd] = (f16)(v * scale);
                    else if (tp == 1) k_s[hh][row][colhd] = (f16)v;
                    else              vt_s[hh][colhd][row] = (f16)v;
                }
        }
        __syncthreads();  // all Q/K/Vt tiles visible

        #pragma unroll
        for (int hh = 0; hh < 2; ++hh) {
            int head = hp * 2 + hh;
            // QK^T for own 16 rows (m-frag = wv)
            f16x8 qf = *(const f16x8*)&q_s[hh][wv * 16 + fr][fq * 8];
            f32x4 s[4];
            #pragma unroll
            for (int j = 0; j < 4; ++j) {
                f16x8 kf = *(const f16x8*)&k_s[hh][j * 16 + fr][fq * 8];
                s[j] = __builtin_amdgcn_mfma_f32_16x16x32_f16(qf, kf, zero4, 0, 0, 0);
            }
            // softmax (rows zq spread over 16-lane groups; scale folded into Q)
            #pragma unroll
            for (int r = 0; r < 4; ++r) {
                int zq = wv * 16 + fq * 4 + r;
                int zd = zq >> 4, zh = (zq >> 2) & 3, zw = zq & 3;
                float tv[4];
                float mx = -1e30f;
                #pragma unroll
                for (int j = 0; j < 4; ++j) {
                    int m = j * 16 + fr;
                    int md = m >> 4, mh = (m >> 2) & 3, mw = m & 3;
                    int idx = (zd - md + 3) * 49 + (zh - mh + 3) * 7 + (zw - mw + 3);
                    float v = s[j][r] + rpb[idx * HEADS + head];
                    tv[j] = v;
                    mx = fmaxf(mx, v);
                }
                mx = fmaxf(mx, __shfl_xor(mx, 1));
                mx = fmaxf(mx, __shfl_xor(mx, 2));
                mx = fmaxf(mx, __shfl_xor(mx, 4));
                mx = fmaxf(mx, __shfl_xor(mx, 8));
                float sum = 0.f;
                #pragma unroll
                for (int j = 0; j < 4; ++j) { tv[j] = expf(tv[j] - mx); sum += tv[j]; }
                sum += __shfl_xor(sum, 1);
                sum += __shfl_xor(sum, 2);
                sum += __shfl_xor(sum, 4);
                sum += __shfl_xor(sum, 8);
                float is = 1.0f / sum;
                #pragma unroll
                for (int j = 0; j < 4; ++j) P[zq][j * 16 + fr] = (f16)(tv[j] * is);
            }
            // PV for own rows (P rows are wave-private; vt barriered above)
            f32x4 oacc[2] = {zero4, zero4};
            #pragma unroll
            for (int jd = 0; jd < 2; ++jd)
                #pragma unroll
                for (int ks = 0; ks < 2; ++ks) {
                    f16x8 pa = *(const f16x8*)&P[wv * 16 + fr][ks * 32 + fq * 8];
                    f16x8 vb = *(const f16x8*)&vt_s[hh][jd * 16 + fr][ks * 32 + fq * 8];
                    oacc[jd] = __builtin_amdgcn_mfma_f32_16x16x32_f16(pa, vb, oacc[jd], 0, 0, 0);
                }
            #pragma unroll
            for (int jd = 0; jd < 2; ++jd)
                #pragma unroll
                for (int r = 0; r < 4; ++r)
                    yg[(size_t)(wv * 16 + fq * 4 + r) * DIM + head * 32 + jd * 16 + fr]
                        = (f16)oacc[jd][r];
        }
        __syncthreads();  // protect q/k/vt before next head-pair overwrites
    }
}

// ---------- fused MLP: out = GELU(y@W1+b1)@W2 + b2 + res (in-place res) -----
__global__ __launch_bounds__(512)
void fmlp_kernel(const f16* __restrict__ Yh, const f16* __restrict__ w1t,
                 const f16* __restrict__ w2t, const float* __restrict__ b1,
                 const float* __restrict__ b2, float* __restrict__ outp)
{
    __shared__ f16 y_s[128][392];
    __shared__ f16 hid_s[128][136];
    int tid = threadIdx.x, lane = tid & 63, wv = tid >> 6;
    int fr = lane & 15, fq = lane >> 4;
    int bm = blockIdx.x << 7;

    // stage y rows (4 threads/row)
    {
        int row = tid >> 2, c0 = (tid & 3) * 96;
        const f16* yg = Yh + (size_t)(bm + row) * DIM + c0;
        #pragma unroll
        for (int i = 0; i < 12; ++i)
            *(f16x8*)&y_s[row][c0 + i * 8] = *(const f16x8*)(yg + i * 8);
    }
    __syncthreads();

    int m0a = (wv >> 1) << 5, n0a = (wv & 1) << 6;   // GEMM1: 4Mx2N waves
    int m0b = (wv >> 2) << 6, n0b = (wv & 3) * 96;   // GEMM2: 2Mx4N waves

    f32x4 zero4 = {0.f, 0.f, 0.f, 0.f};
    f32x4 acc2[4][6];
    #pragma unroll
    for (int i = 0; i < 4; ++i)
        #pragma unroll
        for (int j = 0; j < 6; ++j) acc2[i][j] = zero4;

    for (int ht = 0; ht < 12; ++ht) {
        // ---- GEMM1: 128x128 hidden tile, K=384
        f32x4 acc1[2][4];
        #pragma unroll
        for (int im = 0; im < 2; ++im)
            #pragma unroll
            for (int jn = 0; jn < 4; ++jn) acc1[im][jn] = zero4;
        #pragma unroll
        for (int kk = 0; kk < 12; ++kk) {
            f16x8 a[2];
            #pragma unroll
            for (int im = 0; im < 2; ++im)
                a[im] = *(const f16x8*)&y_s[m0a + im * 16 + fr][kk * 32 + fq * 8];
            #pragma unroll
            for (int jn = 0; jn < 4; ++jn) {
                int nh = ht * 128 + n0a + jn * 16 + fr;
                f16x8 b = *(const f16x8*)(w1t + (size_t)nh * 384 + kk * 32 + fq * 8);
                #pragma unroll
                for (int im = 0; im < 2; ++im)
                    acc1[im][jn] = __builtin_amdgcn_mfma_f32_16x16x32_f16(a[im], b, acc1[im][jn], 0, 0, 0);
            }
        }
        __syncthreads();  // prior GEMM2 reads of hid_s complete
        // ---- bias + exact GELU -> hid_s (fp16)
        #pragma unroll
        for (int im = 0; im < 2; ++im)
            #pragma unroll
            for (int jn = 0; jn < 4; ++jn) {
                float bi = b1[ht * 128 + n0a + jn * 16 + fr];
                #pragma unroll
                for (int r = 0; r < 4; ++r) {
                    float v = acc1[im][jn][r] + bi;
                    v = 0.5f * v * (1.0f + erff(v * 0.70710678118654752f));
                    hid_s[m0a + im * 16 + fq * 4 + r][n0a + jn * 16 + fr] = (f16)v;
                }
            }
        __syncthreads();  // hid_s visible
        // ---- GEMM2 partial: K = 128
        #pragma unroll
        for (int ks = 0; ks < 4; ++ks) {
            f16x8 a[4];
            #pragma unroll
            for (int i = 0; i < 4; ++i)
                a[i] = *(const f16x8*)&hid_s[m0b + i * 16 + fr][ks * 32 + fq * 8];
            #pragma unroll
            for (int j = 0; j < 6; ++j) {
                int n = n0b + j * 16 + fr;
                f16x8 b = *(const f16x8*)(w2t + (size_t)n * 1536 + ht * 128 + ks * 32 + fq * 8);
                #pragma unroll
                for (int i = 0; i < 4; ++i)
                    acc2[i][j] = __builtin_amdgcn_mfma_f32_16x16x32_f16(a[i], b, acc2[i][j], 0, 0, 0);
            }
        }
    }
    // ---- epilogue: + b2 + res (out aliases res; same-thread RMW)
    #pragma unroll
    for (int i = 0; i < 4; ++i)
        #pragma unroll
        for (int j = 0; j < 6; ++j) {
            int n = n0b + j * 16 + fr;
            float bi = b2[n];
            #pragma unroll
            for (int r = 0; r < 4; ++r) {
                int m = bm + m0b + i * 16 + fq * 4 + r;
                size_t oidx = (size_t)m * DIM + n;
                outp[oidx] = acc2[i][j][r] + bi + outp[oidx];
            }
        }
}

extern "C" void kernel_launch(void* const* d_in, const int* in_sizes, int n_in,
                              void* d_out, int out_size, void* d_ws, size_t ws_size,
                              hipStream_t stream)
{
    const float* x      = (const float*)d_in[0];
    const float* ln1_g  = (const float*)d_in[1];
    const float* ln1_b  = (const float*)d_in[2];
    const float* qkv_w  = (const float*)d_in[3];
    const float* qkv_b  = (const float*)d_in[4];
    const float* rpb    = (const float*)d_in[5];
    const float* proj_w = (const float*)d_in[6];
    const float* proj_b = (const float*)d_in[7];
    const float* ln2_g  = (const float*)d_in[8];
    const float* ln2_b  = (const float*)d_in[9];
    const float* mlp_w1 = (const float*)d_in[10];
    const float* mlp_b1 = (const float*)d_in[11];
    const float* mlp_w2 = (const float*)d_in[12];
    const float* mlp_b2 = (const float*)d_in[13];
    float* out = (float*)d_out;

    // ws layout (halves): Wt x4 (3.5MB) | Yh 65536x384 (50MB). No CH anymore.
    f16* wq = (f16*)d_ws;                       // [1152][384]
    f16* wp = wq + 1152 * 384;                  // [384][384]
    f16* w1 = wp + 384 * 384;                   // [1536][384]
    f16* w2 = w1 + 1536 * 384;                  // [384][1536]
    f16* Yh = w2 + 384 * 1536;

    // 0. weight convert+transpose (fp32 [K][N] -> fp16 [N][K])
    wcvt_kernel<<<dim3(3, 1152), 128, 0, stream>>>(qkv_w, wq, 1152, 384);
    wcvt_kernel<<<dim3(3, 384),  128, 0, stream>>>(proj_w, wp, 384, 384);
    wcvt_kernel<<<dim3(3, 1536), 128, 0, stream>>>(mlp_w1, w1, 1536, 384);
    wcvt_kernel<<<dim3(12, 384), 128, 0, stream>>>(mlp_w2, w2, 384, 1536);

    // 1. LN1 + roll + window partition -> Yh (fp16)
    ln_kernel<true><<<MTOT, 128, 0, stream>>>(x, ln1_g, ln1_b, Yh);

    // 2. fused QKV + attention (Yh in-place: y_win -> o_win)
    fqa_kernel<<<1024, 256, 0, stream>>>(Yh, wq, qkv_b, rpb);

    // 3. proj GEMM + window-reverse+roll + residual -> d_out (fp32)
    gemm_kernel<<<dim3(3, MTOT / 128), 256, 0, stream>>>(
        Yh, wp, proj_b, x, out, 384, 384);

    // 4. LN2: d_out -> Yh (fp16)
    ln_kernel<false><<<MTOT, 128, 0, stream>>>(out, ln2_g, ln2_b, Yh);

    // 5. fused MLP (+ residual from/into d_out)
    fmlp_kernel<<<MTOT / 128, 512, 0, stream>>>(Yh, w1, w2, mlp_b1, mlp_b2, out);
}